// Round 2
// baseline (221.514 us; speedup 1.0000x reference)
//
#include <hip/hip_runtime.h>

#define HH 1024
#define LL 512
static constexpr float C_SCALE = 2.8853900817779268f; // 2*log2(e)

// ---------------------------------------------------------------------------
// Kernel 1: projections (fp32 VALU GEMM, no fp32 MFMA on CDNA4)
//   ap[l][o] = (sum_k lm[l,k]*W1[o,k]        + b1[o]) * C_SCALE
//   bp[l][o] = (sum_k lm[l,k]*W1[o,1024+k])          * C_SCALE
// tile: 32 l x 64 o, K-chunk 64. grid (HH/64, LL/32) = (16,16) = 256 blocks.
// ---------------------------------------------------------------------------
__global__ __launch_bounds__(256) void proj_kernel(
    const float* __restrict__ lm, const float* __restrict__ W1,
    const float* __restrict__ b1, float* __restrict__ ap,
    float* __restrict__ bp)
{
    __shared__ float lm_s[32][68];   // +4 pad: 16B-aligned rows, no bank hot-spot
    __shared__ float wa_s[64][68];
    __shared__ float wb_s[64][68];

    const int tid   = threadIdx.x;
    const int tx    = tid & 15;   // o direction (4 o each, stride 16)
    const int ty    = tid >> 4;   // l direction (2 l each)
    const int obase = blockIdx.x * 64;
    const int lbase = blockIdx.y * 32;

    float acc_a[2][4] = {{0.f,0.f,0.f,0.f},{0.f,0.f,0.f,0.f}};
    float acc_b[2][4] = {{0.f,0.f,0.f,0.f},{0.f,0.f,0.f,0.f}};

    for (int kb = 0; kb < HH; kb += 64) {
        __syncthreads();
        // stage lm tile: 32 rows x 64 floats = 512 float4, 2 per thread
        {
            int p = tid;
#pragma unroll
            for (int it = 0; it < 2; ++it, p += 256) {
                const int row = p >> 4, c4 = p & 15;
                const float4 v = *(const float4*)&lm[(lbase + row) * HH + kb + c4 * 4];
                *(float4*)&lm_s[row][c4 * 4] = v;
            }
            // stage W1 halves: 64 rows x 64 floats each = 1024 float4, 4/thread
            p = tid;
#pragma unroll
            for (int it = 0; it < 4; ++it, p += 256) {
                const int row = p >> 4, c4 = p & 15;
                const long base = (long)(obase + row) * 2048 + kb + c4 * 4;
                const float4 va = *(const float4*)&W1[base];
                const float4 vb = *(const float4*)&W1[base + 1024];
                *(float4*)&wa_s[row][c4 * 4] = va;
                *(float4*)&wb_s[row][c4 * 4] = vb;
            }
        }
        __syncthreads();

#pragma unroll
        for (int k4 = 0; k4 < 16; ++k4) {
            float4 lv[2];
            lv[0] = *(const float4*)&lm_s[ty * 2 + 0][k4 * 4];
            lv[1] = *(const float4*)&lm_s[ty * 2 + 1][k4 * 4];
#pragma unroll
            for (int q = 0; q < 4; ++q) {
                const int o = tx + q * 16;
                const float4 av = *(const float4*)&wa_s[o][k4 * 4];
                const float4 bv = *(const float4*)&wb_s[o][k4 * 4];
#pragma unroll
                for (int l = 0; l < 2; ++l) {
                    acc_a[l][q] = __builtin_fmaf(lv[l].x, av.x, acc_a[l][q]);
                    acc_a[l][q] = __builtin_fmaf(lv[l].y, av.y, acc_a[l][q]);
                    acc_a[l][q] = __builtin_fmaf(lv[l].z, av.z, acc_a[l][q]);
                    acc_a[l][q] = __builtin_fmaf(lv[l].w, av.w, acc_a[l][q]);
                    acc_b[l][q] = __builtin_fmaf(lv[l].x, bv.x, acc_b[l][q]);
                    acc_b[l][q] = __builtin_fmaf(lv[l].y, bv.y, acc_b[l][q]);
                    acc_b[l][q] = __builtin_fmaf(lv[l].z, bv.z, acc_b[l][q]);
                    acc_b[l][q] = __builtin_fmaf(lv[l].w, bv.w, acc_b[l][q]);
                }
            }
        }
    }

#pragma unroll
    for (int l = 0; l < 2; ++l) {
#pragma unroll
        for (int q = 0; q < 4; ++q) {
            const int gl = lbase + ty * 2 + l;
            const int go = obase + tx + q * 16;
            ap[gl * HH + go] = (acc_a[l][q] + b1[go]) * C_SCALE;
            bp[gl * HH + go] = acc_b[l][q] * C_SCALE;
        }
    }
}

// ---------------------------------------------------------------------------
// Kernel 2: pairwise tanh contraction.
//   out[i][j][c] = sum_h tanh-form(ap'[j,h] + bp'[i,h]) * W2[c,h] + b2[c]
// where ap'/bp' are pre-scaled by 2*log2(e) (and b1 folded into ap').
// tanh(x) = 1 - 2/(exp2(cx)+1).
// tile: 32 i x 16 j per block; thread owns (i, i+16) x (j). grid (32,16)=512.
// ---------------------------------------------------------------------------
__global__ __launch_bounds__(256, 2) void pair_kernel(
    const float* __restrict__ ap, const float* __restrict__ bp,
    const float* __restrict__ W2, const float* __restrict__ b2,
    float* __restrict__ out)
{
    __shared__ float a_s[16][132];  // +4 pad: 16B-aligned rows, 2-way banks (free)
    __shared__ float b_s[32][132];

    const int tid   = threadIdx.x;
    const int tx    = tid & 15;   // j
    const int ty    = tid >> 4;   // i (rows ty and ty+16)
    const int jbase = blockIdx.x * 16;
    const int ibase = blockIdx.y * 32;

    float acc00 = 0.f, acc01 = 0.f, acc10 = 0.f, acc11 = 0.f;

    for (int kb = 0; kb < HH; kb += 128) {
        __syncthreads();
        // stage 48 rows x 128 floats = 1536 float4, 6 per thread
        int p = tid;
#pragma unroll
        for (int it = 0; it < 6; ++it, p += 256) {
            const int row = p >> 5;   // 0..47
            const int c4  = p & 31;
            if (row < 16) {
                const float4 v = *(const float4*)&ap[(jbase + row) * HH + kb + c4 * 4];
                *(float4*)&a_s[row][c4 * 4] = v;
            } else {
                const float4 v = *(const float4*)&bp[(ibase + row - 16) * HH + kb + c4 * 4];
                *(float4*)&b_s[row - 16][c4 * 4] = v;
            }
        }
        __syncthreads();

        const float* __restrict__ w2a = W2 + kb;
        const float* __restrict__ w2b = W2 + HH + kb;
#pragma unroll 16
        for (int h = 0; h < 128; ++h) {
            const float av  = a_s[tx][h];
            const float bv0 = b_s[ty][h];
            const float bv1 = b_s[ty + 16][h];
            const float w0  = w2a[h];   // uniform address -> scalar load
            const float w1  = w2b[h];
            const float y0 = av + bv0;
            const float y1 = av + bv1;
            const float e0 = __builtin_amdgcn_exp2f(y0);
            const float e1 = __builtin_amdgcn_exp2f(y1);
            const float r0 = __builtin_amdgcn_rcpf(e0 + 1.0f);
            const float r1 = __builtin_amdgcn_rcpf(e1 + 1.0f);
            const float t0 = __builtin_fmaf(-2.0f, r0, 1.0f);
            const float t1 = __builtin_fmaf(-2.0f, r1, 1.0f);
            acc00 = __builtin_fmaf(t0, w0, acc00);
            acc01 = __builtin_fmaf(t0, w1, acc01);
            acc10 = __builtin_fmaf(t1, w0, acc10);
            acc11 = __builtin_fmaf(t1, w1, acc11);
        }
    }

    const float bb0 = b2[0];
    const float bb1 = b2[1];
    const int j  = jbase + tx;
    const int i0 = ibase + ty;
    const int i1 = ibase + ty + 16;
    float2* o2 = (float2*)out;
    o2[i0 * LL + j] = make_float2(acc00 + bb0, acc01 + bb1);
    o2[i1 * LL + j] = make_float2(acc10 + bb0, acc11 + bb1);
}

// ---------------------------------------------------------------------------
// Kernel 3: in-place symmetrization over (i,j). Each unordered pair handled by
// exactly one thread (the i<j one) -> no write hazards.
// ---------------------------------------------------------------------------
__global__ __launch_bounds__(256) void sym_kernel(float* __restrict__ out)
{
    const int idx = blockIdx.x * 256 + threadIdx.x;  // 0..262143
    const int i = idx >> 9;
    const int j = idx & 511;
    if (j > i) {
        float2* o2 = (float2*)out;
        const float2 u = o2[i * LL + j];
        const float2 v = o2[j * LL + i];
        const float2 m = make_float2((u.x + v.x) * 0.5f, (u.y + v.y) * 0.5f);
        o2[i * LL + j] = m;
        o2[j * LL + i] = m;
    }
}

extern "C" void kernel_launch(void* const* d_in, const int* in_sizes, int n_in,
                              void* d_out, int out_size, void* d_ws, size_t ws_size,
                              hipStream_t stream)
{
    const float* lm = (const float*)d_in[0];
    const float* W1 = (const float*)d_in[1];
    const float* b1 = (const float*)d_in[2];
    const float* W2 = (const float*)d_in[3];
    const float* b2 = (const float*)d_in[4];
    float* out = (float*)d_out;

    float* ap = (float*)d_ws;            // 512*1024 floats, pre-scaled, b1 folded
    float* bp = ap + (size_t)LL * HH;    // 512*1024 floats, pre-scaled

    dim3 g1(HH / 64, LL / 32);           // (16,16)
    proj_kernel<<<g1, 256, 0, stream>>>(lm, W1, b1, ap, bp);

    dim3 g2(LL / 16, LL / 32);           // (32,16) = 512 blocks
    pair_kernel<<<g2, 256, 0, stream>>>(ap, bp, W2, b2, out);

    sym_kernel<<<(LL * LL) / 256, 256, 0, stream>>>(out);
}

// Round 3
// 156.464 us; speedup vs baseline: 1.4158x; 1.4158x over previous
//
#include <hip/hip_runtime.h>

#define HH 1024
#define LL 512

typedef __attribute__((ext_vector_type(8))) short bf16x8;
typedef __attribute__((ext_vector_type(4))) float f32x4;

// tanh(x) = 1 - 2/(exp2(2*log2(e)*x)+1)  (exact form, hw exp2/rcp)
static __device__ __forceinline__ float fast_tanh(float x) {
    const float c = 2.8853900817779268f; // 2*log2(e)
    const float e = __builtin_amdgcn_exp2f(c * x);
    const float r = __builtin_amdgcn_rcpf(e + 1.0f);
    return __builtin_fmaf(-2.0f, r, 1.0f);
}

static __device__ __forceinline__ ushort f2bf(float f) {
    unsigned u = __builtin_bit_cast(unsigned, f);
    u += 0x7fffu + ((u >> 16) & 1u);   // round-to-nearest-even
    return (ushort)(u >> 16);
}

// ---------------------------------------------------------------------------
// Kernel 0: fp32 -> bf16 convert.
//   lm16[l][k]  = bf16(lm[l][k])                          (512 x 1024)
//   B16[n][k]   = bf16(W1[(n&1023)*2048 + (n>>10)*1024 + k])  (2048 x 1024)
//     n <  1024: Wa rows (o-major, k-contiguous);  n >= 1024: Wb rows.
// ---------------------------------------------------------------------------
__global__ __launch_bounds__(256) void convert_kernel(
    const float* __restrict__ lm, const float* __restrict__ W1,
    ushort* __restrict__ lm16, ushort* __restrict__ B16)
{
    const int q = blockIdx.x * 256 + threadIdx.x;     // float4-quad index
    if (q < 131072) {                                 // 512*1024/4
        const float4 v = ((const float4*)lm)[q];
        ushort4 o; o.x=f2bf(v.x); o.y=f2bf(v.y); o.z=f2bf(v.z); o.w=f2bf(v.w);
        ((ushort4*)lm16)[q] = o;
    } else {
        const int p = q - 131072;                     // 0 .. 2048*256-1
        const int n = p >> 8, k4 = p & 255;
        const float4 v = *(const float4*)&W1[(n & 1023) * 2048 + (n >> 10) * 1024 + k4 * 4];
        ushort4 o; o.x=f2bf(v.x); o.y=f2bf(v.y); o.z=f2bf(v.z); o.w=f2bf(v.w);
        ((ushort4*)B16)[p] = o;
    }
}

// ---------------------------------------------------------------------------
// Kernel 1: bf16 MFMA projection + tanh epilogue.
//   acc[l][n] = sum_k lm16[l][k] * B16[n][k]   (gemm_bt form, m92/m97 layout)
//   n < 1024:  Ta[l][n]      = tanh(acc + b1[n])
//   n >= 1024: Tb[l][n-1024] = tanh(acc)
// Block tile 32m x 64n, 4 waves each 16m x 32n (2 MFMA col-tiles). BK=64.
// Grid (2048/64, 512/32) = (32,16) = 512 blocks.
// LDS rows padded to 72 bf16 (stride 144B = 36 dwords, ≡4 mod 32 banks: all
// frag reads and staged writes are 2-way max = free).
// ---------------------------------------------------------------------------
__global__ __launch_bounds__(256) void proj_mfma_kernel(
    const ushort* __restrict__ lm16, const ushort* __restrict__ B16,
    const float* __restrict__ b1, float* __restrict__ Ta, float* __restrict__ Tb)
{
    __shared__ ushort As[32][72];
    __shared__ ushort Bs[64][72];

    const int tid  = threadIdx.x;
    const int lane = tid & 63;
    const int w    = tid >> 6;
    const int mbase = blockIdx.y * 32;
    const int nbase = blockIdx.x * 64;
    const int wm = (w & 1) * 16;
    const int wn = (w >> 1) * 32;

    f32x4 acc0 = {0.f, 0.f, 0.f, 0.f};
    f32x4 acc1 = {0.f, 0.f, 0.f, 0.f};

    const int srow = tid >> 3;        // 0..31
    const int sc8  = (tid & 7) * 8;   // bf16 column, 8-elem groups

    const int mrow = lane & 15;       // A-frag m / B-frag n
    const int q8   = (lane >> 4) * 8; // k offset within 32-k step

    for (int kb = 0; kb < HH; kb += 64) {
        __syncthreads();
        *(uint4*)&As[srow][sc8]      = *(const uint4*)&lm16[(mbase + srow) * HH + kb + sc8];
        *(uint4*)&Bs[srow][sc8]      = *(const uint4*)&B16[(nbase + srow) * HH + kb + sc8];
        *(uint4*)&Bs[srow + 32][sc8] = *(const uint4*)&B16[(nbase + srow + 32) * HH + kb + sc8];
        __syncthreads();

#pragma unroll
        for (int s = 0; s < 2; ++s) {
            const bf16x8 a  = *(const bf16x8*)&As[wm + mrow][s * 32 + q8];
            const bf16x8 b0 = *(const bf16x8*)&Bs[wn + mrow][s * 32 + q8];
            const bf16x8 b1f = *(const bf16x8*)&Bs[wn + 16 + mrow][s * 32 + q8];
            acc0 = __builtin_amdgcn_mfma_f32_16x16x32_bf16(a, b0, acc0, 0, 0, 0);
            acc1 = __builtin_amdgcn_mfma_f32_16x16x32_bf16(a, b1f, acc1, 0, 0, 0);
        }
    }

    // Epilogue: D mapping col=lane&15 (n), row=(lane>>4)*4+reg (m).
    const int col = lane & 15;
    const int rq  = (lane >> 4) * 4;
#pragma unroll
    for (int t = 0; t < 2; ++t) {
        const f32x4 acc = t ? acc1 : acc0;
        const int n_g = nbase + wn + t * 16 + col;
        const int m0  = mbase + wm + rq;
        if (n_g < HH) {                       // uniform per 16-wide tile
            const float bb = b1[n_g];
#pragma unroll
            for (int r = 0; r < 4; ++r)
                Ta[(m0 + r) * HH + n_g] = fast_tanh(acc[r] + bb);
        } else {
#pragma unroll
            for (int r = 0; r < 4; ++r)
                Tb[(m0 + r) * HH + (n_g - HH)] = fast_tanh(acc[r]);
        }
    }
}

// ---------------------------------------------------------------------------
// Kernel 2: pairwise contraction via tanh addition formula (no exp in loop).
//   t = (ta + tb) / (1 + ta*tb);  out[i][j][c] = sum_h t * W2[c,h] + b2[c]
// One rcp per TWO outputs: r = rcp(d0*d1); r0 = r*d1; r1 = r*d0.
// Tile 32i x 16j, thread owns (ty, ty+16) x (tx). Grid (32,16) = 512 blocks.
// W2 staged once into LDS; inner-loop W2 reads are wave-uniform broadcasts.
// ---------------------------------------------------------------------------
__global__ __launch_bounds__(256) void pair_kernel(
    const float* __restrict__ Ta, const float* __restrict__ Tb,
    const float* __restrict__ W2, const float* __restrict__ b2,
    float* __restrict__ out)
{
    __shared__ float a_s[16][132];   // stride 132 ≡ 4 mod 32: 2-way max = free
    __shared__ float b_s[32][132];
    __shared__ float w0_s[HH], w1_s[HH];

    const int tid   = threadIdx.x;
    const int tx    = tid & 15;   // j
    const int ty    = tid >> 4;   // i rows ty, ty+16
    const int jbase = blockIdx.x * 16;
    const int ibase = blockIdx.y * 32;

    // stage W2 (2 x 1024 f32 = 512 float4) once
    {
        int p = tid;
#pragma unroll
        for (int it = 0; it < 2; ++it, p += 256) {
            const float4 v = ((const float4*)W2)[p];
            if (p < 256) ((float4*)w0_s)[p] = v;
            else         ((float4*)w1_s)[p - 256] = v;
        }
    }

    float acc00 = 0.f, acc01 = 0.f, acc10 = 0.f, acc11 = 0.f;

    for (int kb = 0; kb < HH; kb += 128) {
        __syncthreads();
        int p = tid;
#pragma unroll
        for (int it = 0; it < 6; ++it, p += 256) {
            const int row = p >> 5;   // 0..47
            const int c4  = p & 31;
            if (row < 16)
                *(float4*)&a_s[row][c4 * 4] = *(const float4*)&Ta[(jbase + row) * HH + kb + c4 * 4];
            else
                *(float4*)&b_s[row - 16][c4 * 4] = *(const float4*)&Tb[(ibase + row - 16) * HH + kb + c4 * 4];
        }
        __syncthreads();

#pragma unroll 8
        for (int h4 = 0; h4 < 32; ++h4) {
            const float4 ta4  = *(const float4*)&a_s[tx][h4 * 4];
            const float4 tb04 = *(const float4*)&b_s[ty][h4 * 4];
            const float4 tb14 = *(const float4*)&b_s[ty + 16][h4 * 4];
            const float4 w04  = *(const float4*)&w0_s[kb + h4 * 4];
            const float4 w14  = *(const float4*)&w1_s[kb + h4 * 4];

#define DO_H(TA, TB0, TB1, W0, W1V)                                  \
            {                                                        \
                const float n0 = (TA) + (TB0);                       \
                const float n1 = (TA) + (TB1);                       \
                const float d0 = __builtin_fmaf((TA), (TB0), 1.0f);  \
                const float d1 = __builtin_fmaf((TA), (TB1), 1.0f);  \
                const float r  = __builtin_amdgcn_rcpf(d0 * d1);     \
                const float t0 = n0 * (r * d1);                      \
                const float t1 = n1 * (r * d0);                      \
                acc00 = __builtin_fmaf(t0, (W0), acc00);             \
                acc01 = __builtin_fmaf(t0, (W1V), acc01);            \
                acc10 = __builtin_fmaf(t1, (W0), acc10);             \
                acc11 = __builtin_fmaf(t1, (W1V), acc11);            \
            }
            DO_H(ta4.x, tb04.x, tb14.x, w04.x, w14.x)
            DO_H(ta4.y, tb04.y, tb14.y, w04.y, w14.y)
            DO_H(ta4.z, tb04.z, tb14.z, w04.z, w14.z)
            DO_H(ta4.w, tb04.w, tb14.w, w04.w, w14.w)
#undef DO_H
        }
    }

    const float bb0 = b2[0];
    const float bb1 = b2[1];
    const int j  = jbase + tx;
    const int i0 = ibase + ty;
    const int i1 = ibase + ty + 16;
    float2* o2 = (float2*)out;
    o2[i0 * LL + j] = make_float2(acc00 + bb0, acc01 + bb1);
    o2[i1 * LL + j] = make_float2(acc10 + bb0, acc11 + bb1);
}

// ---------------------------------------------------------------------------
// Kernel 3: in-place symmetrization (i<j thread owns the pair).
// ---------------------------------------------------------------------------
__global__ __launch_bounds__(256) void sym_kernel(float* __restrict__ out)
{
    const int idx = blockIdx.x * 256 + threadIdx.x;
    const int i = idx >> 9;
    const int j = idx & 511;
    if (j > i) {
        float2* o2 = (float2*)out;
        const float2 u = o2[i * LL + j];
        const float2 v = o2[j * LL + i];
        const float2 m = make_float2((u.x + v.x) * 0.5f, (u.y + v.y) * 0.5f);
        o2[i * LL + j] = m;
        o2[j * LL + i] = m;
    }
}

extern "C" void kernel_launch(void* const* d_in, const int* in_sizes, int n_in,
                              void* d_out, int out_size, void* d_ws, size_t ws_size,
                              hipStream_t stream)
{
    const float* lm = (const float*)d_in[0];
    const float* W1 = (const float*)d_in[1];
    const float* b1 = (const float*)d_in[2];
    const float* W2 = (const float*)d_in[3];
    const float* b2 = (const float*)d_in[4];
    float* out = (float*)d_out;

    ushort* lm16 = (ushort*)d_ws;                               // 1 MB
    ushort* B16  = (ushort*)((char*)d_ws + (size_t)(1 << 20));  // 4 MB
    float*  Ta   = (float*) ((char*)d_ws + (size_t)(5 << 20));  // 2 MB
    float*  Tb   = (float*) ((char*)d_ws + (size_t)(7 << 20));  // 2 MB

    convert_kernel<<<2560, 256, 0, stream>>>(lm, W1, lm16, B16);
    proj_mfma_kernel<<<dim3(32, 16), 256, 0, stream>>>(lm16, B16, b1, Ta, Tb);
    pair_kernel<<<dim3(32, 16), 256, 0, stream>>>(Ta, Tb, W2, b2, out);
    sym_kernel<<<(LL * LL) / 256, 256, 0, stream>>>(out);
}